// Round 9
// baseline (112.410 us; speedup 1.0000x reference)
//
#include <hip/hip_runtime.h>
#include <stdint.h>

#define IN_F 2048
#define OUT_F 2048
#define BM 256
#define BN 256
#define NT 16               // K-tiles of 128 bytes

typedef int v4i  __attribute__((ext_vector_type(4)));
typedef int v16i __attribute__((ext_vector_type(16)));

__device__ __forceinline__ void gload_lds16(const void* g, void* l) {
    __builtin_amdgcn_global_load_lds(
        (const __attribute__((address_space(1))) void*)g,
        (__attribute__((address_space(3))) void*)l, 16, 0, 0);
}

// ---------------- Kernel 1: smooth-scale + per-token int8 quant ----------------
__global__ __launch_bounds__(256) void quant_kernel(
    const float* __restrict__ x, const float* __restrict__ ss,
    int8_t* __restrict__ xq, float* __restrict__ xscale, int T)
{
    const int wave = threadIdx.x >> 6;
    const int lane = threadIdx.x & 63;
    const int t = blockIdx.x * 4 + wave;
    if (t >= T) return;

    const float4* xrow = (const float4*)(x + (size_t)t * IN_F);
    const float4* ssv  = (const float4*)ss;

    float4 vals[8];
    float amax = 0.f;
#pragma unroll
    for (int it = 0; it < 8; ++it) {
        int idx = it * 64 + lane;
        float4 v = xrow[idx];
        float4 s = ssv[idx];
        v.x *= s.x; v.y *= s.y; v.z *= s.z; v.w *= s.w;
        vals[it] = v;
        amax = fmaxf(amax, fmaxf(fmaxf(fabsf(v.x), fabsf(v.y)),
                                 fmaxf(fabsf(v.z), fabsf(v.w))));
    }
#pragma unroll
    for (int o = 32; o; o >>= 1) amax = fmaxf(amax, __shfl_xor(amax, o, 64));

    float scale = fmaxf(amax * (1.0f / 127.0f), 1e-8f);
    float inv = 1.0f / scale;
    if (lane == 0) xscale[t] = scale;

    int* out = (int*)(xq + (size_t)t * IN_F);
#pragma unroll
    for (int it = 0; it < 8; ++it) {
        float4 v = vals[it];
        int q0 = (int)fminf(fmaxf(rintf(v.x * inv), -128.f), 127.f);
        int q1 = (int)fminf(fmaxf(rintf(v.y * inv), -128.f), 127.f);
        int q2 = (int)fminf(fmaxf(rintf(v.z * inv), -128.f), 127.f);
        int q3 = (int)fminf(fmaxf(rintf(v.w * inv), -128.f), 127.f);
        out[it * 64 + lane] = (q0 & 255) | ((q1 & 255) << 8) |
                              ((q2 & 255) << 16) | ((q3 & 255) << 24);
    }
}

// ---------------- Kernel 2: pack W into MFMA-fragment order ----------------
// Fragment (colblk, kt, ks), lane l holds 16B: col = colblk*32 + (l&31),
// k = kt*128 + ks*32 + (l>>5)*16 + 0..15.  Byte addr = colblk*65536 + kt*4096
// + ks*1024 + l*16.
__global__ __launch_bounds__(256) void pack_wfrag_kernel(
    const int* __restrict__ w, int8_t* __restrict__ w8f)
{
    const int tau = blockIdx.x * 256 + threadIdx.x;
    const int lane = tau & 63;
    const int rest = tau >> 6;
    const int ks = rest & 3;
    const int kt = (rest >> 2) & 15;
    const int colblk = rest >> 6;
    const int col = colblk * 32 + (lane & 31);
    const int kbase = kt * 128 + ks * 32 + (lane >> 5) * 16;
    const int* src = w + (size_t)col * IN_F + kbase;
    int out[4];
#pragma unroll
    for (int d = 0; d < 4; ++d) {
        int4 v = *(const int4*)(src + d * 4);
        out[d] = (v.x & 255) | ((v.y & 255) << 8) |
                 ((v.z & 255) << 16) | ((v.w & 255) << 24);
    }
    *(int4*)(w8f + (size_t)tau * 16) = *(const int4*)out;
}

// ---------------- Kernel 3: 256x256, 8 waves, 4-phase/K-tile i8 GEMM ------------
// Wave tile 128x64 (acc[4][2] v16i). A in LDS 3-deep; B fragment-direct from L2,
// ping-pong regs split lo(n0)/hi(n1). Per tile, 4 phases; each: {reads/issues,
// bar, prio1, 8 MFMA, prio0, [vmcnt(8)], bar}. vmcnt only at ph1/ph4, never <8
// until the tail (ledger in comments below).
__global__ __launch_bounds__(512, 2) void gemm_kernel(
    const int8_t* __restrict__ Ag,
    const int8_t* __restrict__ Bf,
    const float* __restrict__ xscale,
    const float* __restrict__ wscale,
    const float* __restrict__ bias,
    float* __restrict__ C, int M)
{
    __shared__ __align__(16) int8_t smem[3 * 32768];   // 96 KB: 3 A-slots

    const int tid  = threadIdx.x;
    const int lane = tid & 63;
    const int wave = tid >> 6;
    const int wr = wave >> 2;          // 0..1 (M half)
    const int wc = wave & 3;           // 0..3 (N quarter, 64 cols)
    const int l31 = lane & 31, hi2 = lane >> 5;
    const int asw = l31 & 7;

    // XCD-bijective swizzle: 512 blocks, 8 XCDs, 64 per chunk
    const int lb  = blockIdx.x;
    const int swb = (lb & 7) * 64 + (lb >> 3);
    const int bm = swb >> 3;
    const int bn = swb & 7;
    const size_t arow0 = (size_t)bm * BM;

    const int st_r = tid >> 3;                              // 0..63
    const int st_c = ((tid & 7) ^ ((tid >> 3) & 7)) << 4;   // pre-swizzled src col
    const int aoff = (wr * 128 + l31) * 128;

    const int8_t* bbase = Bf + (size_t)(bn * 8 + wc * 2) * 65536 + lane * 16;

#define STAGE_H(SLOTI, T, H)                                                     \
    do { _Pragma("unroll") for (int i_ = 0; i_ < 2; ++i_)                        \
        gload_lds16(Ag + (arow0 + (H) * 128 + i_ * 64 + st_r) * (size_t)IN_F     \
                        + (size_t)((T) * 128) + st_c,                            \
                    (int8_t*)smem + (SLOTI) * 32768 + (H) * 16384 + i_ * 8192    \
                        + tid * 16);                                             \
    } while (0)

#define LOADB_LO(DST, T)                                                         \
    do { _Pragma("unroll") for (int k_ = 0; k_ < 4; ++k_)                        \
        DST[k_] = *(const v4i*)(bbase + (T) * 4096 + k_ * 1024);                 \
    } while (0)

#define LOADB_HI(DST, T)                                                         \
    do { _Pragma("unroll") for (int k_ = 0; k_ < 4; ++k_)                        \
        DST[4 + k_] = *(const v4i*)(bbase + 65536 + (T) * 4096 + k_ * 1024);     \
    } while (0)

#define RDAP(P)                                                                  \
    do { _Pragma("unroll") for (int j_ = 0; j_ < 2; ++j_)                        \
         _Pragma("unroll") for (int ks_ = 0; ks_ < 4; ++ks_)                     \
        a[j_][ks_] = *(const v4i*)(sp_ + (2 * (P) + j_) * 4096 +                 \
                                   (((ks_ * 2 + hi2) ^ asw) << 4));              \
    } while (0)

#define MF(P, N, BC)                                                             \
    do { __builtin_amdgcn_s_setprio(1);                                          \
        _Pragma("unroll") for (int j_ = 0; j_ < 2; ++j_)                         \
        _Pragma("unroll") for (int ks_ = 0; ks_ < 4; ++ks_)                      \
            acc[2 * (P) + j_][N] = __builtin_amdgcn_mfma_i32_32x32x32_i8(        \
                a[j_][ks_], BC[(N) * 4 + ks_], acc[2 * (P) + j_][N], 0, 0, 0);   \
        __builtin_amdgcn_s_setprio(0); } while (0)

#define BAR __builtin_amdgcn_s_barrier()
#define VMW8 asm volatile("s_waitcnt vmcnt(8)" ::: "memory")
#define VMW4 asm volatile("s_waitcnt vmcnt(4)" ::: "memory")
#define VMW0 asm volatile("s_waitcnt vmcnt(0)" ::: "memory")
#define VNOP ((void)0)

// Ledger (steady t): issue order = blo(t+1)[ph1,4], bhi(t+1)[ph2,4],
// S(t+2)h0[ph3,2], S(t+2)h1[ph4,2]. End-ph1 vmcnt(8): drains bhi(t) [for ph2],
// keeps S(t+1)4+blo(t+1)4. End-ph4 vmcnt(8): drains S(t+1)+blo(t+1) [for t+1
// ph1], keeps bhi(t+1)4+S(t+2)4. Tail: t14 end-ph4 vmcnt(4); t15 ph1 vmcnt(0).
#define KT(T, BC, BX, W1, W4)                                                    \
    do {                                                                         \
        const int8_t* sp_ = (const int8_t*)smem + ((T) % 3) * 32768 + aoff;      \
        /* ph1 */                                                                \
        RDAP(0);                                                                 \
        if ((T) <= 14) LOADB_LO(BX, (T) + 1);                                    \
        BAR; MF(0, 0, BC); W1; BAR;                                              \
        /* ph2 */                                                                \
        if ((T) <= 14) LOADB_HI(BX, (T) + 1);                                    \
        BAR; MF(0, 1, BC); BAR;                                                  \
        /* ph3 */                                                                \
        RDAP(1);                                                                 \
        if ((T) <= 13) STAGE_H(((T) + 2) % 3, (T) + 2, 0);                       \
        BAR; MF(1, 0, BC); BAR;                                                  \
        /* ph4 */                                                                \
        if ((T) <= 13) STAGE_H(((T) + 2) % 3, (T) + 2, 1);                       \
        BAR; MF(1, 1, BC); W4; BAR;                                              \
    } while (0)

    v16i acc[4][2] = {};
    v4i a[2][4];
    v4i B0[8], B1[8];

    // prologue: issue order S(0)4, blo(0)4, S(1)4, bhi(0)4 -> vmcnt(8) drains
    // S(0)+blo(0), keeps S(1)+bhi(0) in flight.
    STAGE_H(0, 0, 0); STAGE_H(0, 0, 1);
    LOADB_LO(B0, 0);
    STAGE_H(1, 1, 0); STAGE_H(1, 1, 1);
    LOADB_HI(B0, 0);
    VMW8;
    BAR;

    KT(0,  B0, B1, VMW8, VMW8);
    KT(1,  B1, B0, VMW8, VMW8);
    KT(2,  B0, B1, VMW8, VMW8);
    KT(3,  B1, B0, VMW8, VMW8);
    KT(4,  B0, B1, VMW8, VMW8);
    KT(5,  B1, B0, VMW8, VMW8);
    KT(6,  B0, B1, VMW8, VMW8);
    KT(7,  B1, B0, VMW8, VMW8);
    KT(8,  B0, B1, VMW8, VMW8);
    KT(9,  B1, B0, VMW8, VMW8);
    KT(10, B0, B1, VMW8, VMW8);
    KT(11, B1, B0, VMW8, VMW8);
    KT(12, B0, B1, VMW8, VMW8);
    KT(13, B1, B0, VMW8, VMW8);
    KT(14, B0, B1, VMW8, VMW4);
    KT(15, B1, B0, VMW0, VNOP);

    // epilogue: 32x32 C/D layout col = lane&31, row = (reg&3)+8*(reg>>2)+4*hi2
    float wsc[2], bs[2];
    int gcol[2];
#pragma unroll
    for (int n = 0; n < 2; ++n) {
        gcol[n] = bn * BN + wc * 64 + n * 32 + l31;
        wsc[n] = wscale[gcol[n]];
        bs[n]  = bias[gcol[n]];
    }
#pragma unroll
    for (int m = 0; m < 4; ++m) {
#pragma unroll
        for (int reg = 0; reg < 16; ++reg) {
            const int row = (reg & 3) + 8 * (reg >> 2) + 4 * hi2;
            const size_t grow = arow0 + wr * 128 + m * 32 + row;
            const float xs = xscale[grow];
            float* crow = C + grow * OUT_F;
#pragma unroll
            for (int n = 0; n < 2; ++n)
                __builtin_nontemporal_store(
                    (float)acc[m][n][reg] * xs * wsc[n] + bs[n], crow + gcol[n]);
        }
    }
#undef STAGE_H
#undef LOADB_LO
#undef LOADB_HI
#undef RDAP
#undef MF
#undef KT
}

extern "C" void kernel_launch(void* const* d_in, const int* in_sizes, int n_in,
                              void* d_out, int out_size, void* d_ws, size_t ws_size,
                              hipStream_t stream)
{
    const float* x      = (const float*)d_in[0];
    const float* ss     = (const float*)d_in[1];
    const float* wscale = (const float*)d_in[2];
    const float* bias   = (const float*)d_in[3];
    const int*   w32    = (const int*)d_in[4];
    float* out = (float*)d_out;

    const int T = in_sizes[0] / IN_F;   // 16384

    int8_t* xq     = (int8_t*)d_ws;
    float*  xscale = (float*)((char*)d_ws + (size_t)T * IN_F);
    int8_t* w8f    = (int8_t*)((char*)d_ws + (size_t)T * IN_F + (size_t)T * 4);

    quant_kernel<<<dim3((T + 3) / 4), dim3(256), 0, stream>>>(x, ss, xq, xscale, T);
    pack_wfrag_kernel<<<dim3(1024), dim3(256), 0, stream>>>(w32, w8f);
    gemm_kernel<<<dim3((T / BM) * (OUT_F / BN)), dim3(512), 0, stream>>>(
        xq, w8f, xscale, wscale, bias, out, T);
}

// Round 11
// 110.974 us; speedup vs baseline: 1.0129x; 1.0129x over previous
//
#include <hip/hip_runtime.h>
#include <stdint.h>

#define IN_F 2048
#define OUT_F 2048
#define BM 256
#define BN 256
#define NT 16               // K-tiles of 128 bytes

typedef int v4i  __attribute__((ext_vector_type(4)));
typedef int v16i __attribute__((ext_vector_type(16)));

__device__ __forceinline__ void gload_lds16(const void* g, void* l) {
    __builtin_amdgcn_global_load_lds(
        (const __attribute__((address_space(1))) void*)g,
        (__attribute__((address_space(3))) void*)l, 16, 0, 0);
}

// ---------------- Kernel 1: smooth-scale + per-token int8 quant ----------------
__global__ __launch_bounds__(256) void quant_kernel(
    const float* __restrict__ x, const float* __restrict__ ss,
    int8_t* __restrict__ xq, float* __restrict__ xscale, int T)
{
    const int wave = threadIdx.x >> 6;
    const int lane = threadIdx.x & 63;
    const int t = blockIdx.x * 4 + wave;
    if (t >= T) return;

    const float4* xrow = (const float4*)(x + (size_t)t * IN_F);
    const float4* ssv  = (const float4*)ss;

    float4 vals[8];
    float amax = 0.f;
#pragma unroll
    for (int it = 0; it < 8; ++it) {
        int idx = it * 64 + lane;
        float4 v = xrow[idx];
        float4 s = ssv[idx];
        v.x *= s.x; v.y *= s.y; v.z *= s.z; v.w *= s.w;
        vals[it] = v;
        amax = fmaxf(amax, fmaxf(fmaxf(fabsf(v.x), fabsf(v.y)),
                                 fmaxf(fabsf(v.z), fabsf(v.w))));
    }
#pragma unroll
    for (int o = 32; o; o >>= 1) amax = fmaxf(amax, __shfl_xor(amax, o, 64));

    float scale = fmaxf(amax * (1.0f / 127.0f), 1e-8f);
    float inv = 1.0f / scale;
    if (lane == 0) xscale[t] = scale;

    int* out = (int*)(xq + (size_t)t * IN_F);
#pragma unroll
    for (int it = 0; it < 8; ++it) {
        float4 v = vals[it];
        int q0 = (int)fminf(fmaxf(rintf(v.x * inv), -128.f), 127.f);
        int q1 = (int)fminf(fmaxf(rintf(v.y * inv), -128.f), 127.f);
        int q2 = (int)fminf(fmaxf(rintf(v.z * inv), -128.f), 127.f);
        int q3 = (int)fminf(fmaxf(rintf(v.w * inv), -128.f), 127.f);
        out[it * 64 + lane] = (q0 & 255) | ((q1 & 255) << 8) |
                              ((q2 & 255) << 16) | ((q3 & 255) << 24);
    }
}

// ---------------- Kernel 2: pack W into MFMA-fragment order ----------------
// Fragment (colblk, kt, ks), lane l holds 16B: col = colblk*32 + (l&31),
// k = kt*128 + ks*32 + (l>>5)*16 + 0..15.  Byte addr = colblk*65536 + kt*4096
// + ks*1024 + l*16.
__global__ __launch_bounds__(256) void pack_wfrag_kernel(
    const int* __restrict__ w, int8_t* __restrict__ w8f)
{
    const int tau = blockIdx.x * 256 + threadIdx.x;
    const int lane = tau & 63;
    const int rest = tau >> 6;
    const int ks = rest & 3;
    const int kt = (rest >> 2) & 15;
    const int colblk = rest >> 6;
    const int col = colblk * 32 + (lane & 31);
    const int kbase = kt * 128 + ks * 32 + (lane >> 5) * 16;
    const int* src = w + (size_t)col * IN_F + kbase;
    int out[4];
#pragma unroll
    for (int d = 0; d < 4; ++d) {
        int4 v = *(const int4*)(src + d * 4);
        out[d] = (v.x & 255) | ((v.y & 255) << 8) |
                 ((v.z & 255) << 16) | ((v.w & 255) << 24);
    }
    *(int4*)(w8f + (size_t)tau * 16) = *(const int4*)out;
}

// ---------------- Kernel 3: 256x256, 8 waves, fragment-linear LDS, 4-phase ------
// LDS set (64KB) = A-frags [32KB: f=(gg*4+ks)*1024+l*16] | B-frags [32KB].
// All LDS writes/reads are contiguous 1KB per wave -> zero bank conflicts.
// Read map: ph1 reads A-rounds {J0 (wr=0), J2 (wr=1)} + B-lo; ph2 B-hi;
// ph3 A-rounds {J1, J3}.  Stage plan (tile T stages ALL of T+2, same set,
// each region strictly after its last read):
//   ph2: STA J0, J2   (A last read ph1)
//   ph3: STB J0, J1   (B LDS last read ph2)
//   ph4: STB J2, J3, STA J1, J3   (A J1/J3 last read ph3)
// Ledger: 8 issues/tile; end-of-tile vmcnt(8) drains tile T+1's 8 stages,
// keeps T+2's 8 in flight (>= 1 full tile of latency cover). Tail: KT(14)
// vmcnt(0); KT(15) none. Prologue 16 issues -> vmcnt(8).
__global__ __launch_bounds__(512, 2) void gemm_kernel(
    const int8_t* __restrict__ Ag,
    const int8_t* __restrict__ Bf,
    const float* __restrict__ xscale,
    const float* __restrict__ wscale,
    const float* __restrict__ bias,
    float* __restrict__ C, int M)
{
    __shared__ __align__(16) int8_t smem[2 * 65536];   // 128 KB

    const int tid  = threadIdx.x;
    const int lane = tid & 63;
    const int wave = tid >> 6;
    const int wr = wave >> 2;          // 0..1 (M half)
    const int wc = wave & 3;           // 0..3 (N quarter)
    const int l31 = lane & 31, hi2 = lane >> 5;

    // XCD-bijective swizzle: 512 blocks, 8 XCDs, 64 per chunk
    const int lb  = blockIdx.x;
    const int swb = (lb & 7) * 64 + (lb >> 3);
    const int bm = swb >> 3;
    const int bn = swb & 7;
    const size_t arow0 = (size_t)bm * BM;

    // A-stage per-thread gather geometry: round J covers frags [J*8, J*8+8)
    const int af_ = (tid >> 6);                   // frag-within-round
    const size_t a_rowbyte = (arow0 + (size_t)(af_ >> 2) * 32 + (lane & 31)) * 2048
                             + (af_ & 3) * 32 + (hi2 << 4);

#define STA(SET, T, J)                                                           \
    gload_lds16(Ag + a_rowbyte + (size_t)(J) * 2 * 32 * 2048 + (T) * 128,        \
                (int8_t*)smem + (SET) * 65536 + (J) * 8192 + tid * 16)

#define STB(SET, T, J)                                                           \
    gload_lds16(Bf + (size_t)(bn * 8 + 2 * (J) + (tid >> 8)) * 65536             \
                    + (T) * 4096 + (tid & 255) * 16,                             \
                (int8_t*)smem + (SET) * 65536 + 32768 + (J) * 8192 + tid * 16)

#define RD_ALO(SB)                                                               \
    do { _Pragma("unroll") for (int m_ = 0; m_ < 2; ++m_)                        \
         _Pragma("unroll") for (int k_ = 0; k_ < 4; ++k_)                        \
        aA[m_][k_] = *(const v4i*)((SB) + ((wr * 4 + m_) * 4 + k_) * 1024        \
                                   + lane * 16); } while (0)

#define RD_AHI(SB)                                                               \
    do { _Pragma("unroll") for (int m_ = 0; m_ < 2; ++m_)                        \
         _Pragma("unroll") for (int k_ = 0; k_ < 4; ++k_)                        \
        aA[m_][k_] = *(const v4i*)((SB) + ((wr * 4 + 2 + m_) * 4 + k_) * 1024    \
                                   + lane * 16); } while (0)

#define RD_B(SB, DST, NSEL)                                                      \
    do { _Pragma("unroll") for (int k_ = 0; k_ < 4; ++k_)                        \
        DST[k_] = *(const v4i*)((SB) + 32768 + ((wc * 2 + (NSEL)) * 4 + k_)      \
                                * 1024 + lane * 16); } while (0)

#define MF(MB, N, B)                                                             \
    do { __builtin_amdgcn_s_setprio(1);                                          \
        _Pragma("unroll") for (int k_ = 0; k_ < 4; ++k_)                         \
        _Pragma("unroll") for (int m_ = 0; m_ < 2; ++m_)                         \
            acc[(MB) + m_][N] = __builtin_amdgcn_mfma_i32_32x32x32_i8(           \
                aA[m_][k_], B[k_], acc[(MB) + m_][N], 0, 0, 0);                  \
        __builtin_amdgcn_s_setprio(0); } while (0)

#define BAR __builtin_amdgcn_s_barrier()
#define VMW8 asm volatile("s_waitcnt vmcnt(8)" ::: "memory")
#define VMW0 asm volatile("s_waitcnt vmcnt(0)" ::: "memory")

#define KT(T)                                                                    \
    do {                                                                         \
        const int8_t* sb = (const int8_t*)smem + ((T) & 1) * 65536;              \
        /* ph1: Alo*Blo (reads A J0/J2, B even-cb) */                            \
        RD_ALO(sb); RD_B(sb, bLo, 0);                                            \
        BAR; MF(0, 0, bLo); BAR;                                                 \
        /* ph2: Alo*Bhi (reads B odd-cb); stage A(T+2) J0,J2 */                  \
        RD_B(sb, bHi, 1);                                                        \
        if ((T) <= 13) { STA((T) & 1, (T) + 2, 0); STA((T) & 1, (T) + 2, 2); }   \
        BAR; MF(0, 1, bHi); BAR;                                                 \
        /* ph3: Ahi*Bhi (reads A J1/J3); stage B(T+2) J0,J1 */                   \
        RD_AHI(sb);                                                              \
        if ((T) <= 13) { STB((T) & 1, (T) + 2, 0); STB((T) & 1, (T) + 2, 1); }   \
        BAR; MF(2, 1, bHi); BAR;                                                 \
        /* ph4: Ahi*Blo; stage B(T+2) J2,J3 + A(T+2) J1,J3 */                    \
        if ((T) <= 13) { STB((T) & 1, (T) + 2, 2); STB((T) & 1, (T) + 2, 3);     \
                         STA((T) & 1, (T) + 2, 1); STA((T) & 1, (T) + 2, 3); }   \
        BAR; MF(2, 0, bLo);                                                      \
        if ((T) <= 13) VMW8; else if ((T) == 14) VMW0;                           \
        BAR;                                                                     \
    } while (0)

    v16i acc[4][2] = {};
    v4i aA[2][4], bLo[4], bHi[4];

    // prologue: tile 0 (A+B, 8) then tile 1 (A+B, 8); vmcnt(8) drains tile 0.
    STA(0, 0, 0); STA(0, 0, 1); STA(0, 0, 2); STA(0, 0, 3);
    STB(0, 0, 0); STB(0, 0, 1); STB(0, 0, 2); STB(0, 0, 3);
    STA(1, 1, 0); STA(1, 1, 1); STA(1, 1, 2); STA(1, 1, 3);
    STB(1, 1, 0); STB(1, 1, 1); STB(1, 1, 2); STB(1, 1, 3);
    VMW8;
    BAR;

    KT(0);  KT(1);  KT(2);  KT(3);
    KT(4);  KT(5);  KT(6);  KT(7);
    KT(8);  KT(9);  KT(10); KT(11);
    KT(12); KT(13); KT(14); KT(15);

    // epilogue: 32x32 C/D layout col = lane&31, row = (reg&3)+8*(reg>>2)+4*hi2
    float wsc[2], bs[2];
    int gcol[2];
#pragma unroll
    for (int n = 0; n < 2; ++n) {
        gcol[n] = bn * BN + wc * 64 + n * 32 + l31;
        wsc[n] = wscale[gcol[n]];
        bs[n]  = bias[gcol[n]];
    }
#pragma unroll
    for (int m = 0; m < 4; ++m) {
#pragma unroll
        for (int reg = 0; reg < 16; ++reg) {
            const int row = (reg & 3) + 8 * (reg >> 2) + 4 * hi2;
            const size_t grow = arow0 + wr * 128 + m * 32 + row;
            const float xs = xscale[grow];
            float* crow = C + grow * OUT_F;
#pragma unroll
            for (int n = 0; n < 2; ++n)
                __builtin_nontemporal_store(
                    (float)acc[m][n][reg] * xs * wsc[n] + bs[n], crow + gcol[n]);
        }
    }
#undef STA
#undef STB
#undef RD_ALO
#undef RD_AHI
#undef RD_B
#undef MF
#undef KT
}

extern "C" void kernel_launch(void* const* d_in, const int* in_sizes, int n_in,
                              void* d_out, int out_size, void* d_ws, size_t ws_size,
                              hipStream_t stream)
{
    const float* x      = (const float*)d_in[0];
    const float* ss     = (const float*)d_in[1];
    const float* wscale = (const float*)d_in[2];
    const float* bias   = (const float*)d_in[3];
    const int*   w32    = (const int*)d_in[4];
    float* out = (float*)d_out;

    const int T = in_sizes[0] / IN_F;   // 16384

    int8_t* xq     = (int8_t*)d_ws;
    float*  xscale = (float*)((char*)d_ws + (size_t)T * IN_F);
    int8_t* w8f    = (int8_t*)((char*)d_ws + (size_t)T * IN_F + (size_t)T * 4);

    quant_kernel<<<dim3((T + 3) / 4), dim3(256), 0, stream>>>(x, ss, xq, xscale, T);
    pack_wfrag_kernel<<<dim3(1024), dim3(256), 0, stream>>>(w32, w8f);
    gemm_kernel<<<dim3((T / BM) * (OUT_F / BN)), dim3(512), 0, stream>>>(
        xq, w8f, xscale, wscale, bias, out, T);
}